// Round 1
// baseline (176.147 us; speedup 1.0000x reference)
//
#include <hip/hip_runtime.h>
#include <math.h>

// Folded model (exact algebra, per-token):
//   h      = relu(x @ G1 + b11)                      [400 MACs]
//   h2     = relu(h @ P1 + x @ P2 + f2)              [800 MACs]
//   logits = h2 @ M2 + h @ Q1 + x @ Q2 + f3          [180 MACs]
//   out    = softmax(logits)
// where (layer arrays l=0 at offset 0, l=1 at offset 400):
//   A_l[i][j] = Wv_l[j][i] + Wres_l[i][j]
//   G_l[k][m] = sum_j A_l[k][j] * W1_l[m][j]       (A folded through W1)
//   C1[m'][i] = W2_0[i][m'] ; D1[k][i] = W3_0[i][k] ; e1 = b2_0 + b3_0
//   M2[m][c]  = sum_p Wc[c][p]*W2_1[p][m] ; M3[i][c] = sum_p Wc[c][p]*W3_1[p][i]
//   P1 = C1@G2 ; P2 = D1@G2 ; Q1 = C1@M3 ; Q2 = D1@M3
//   f2 = b1_1 + e1@G2 ; f3 = bc + Wc@(b2_1+b3_1) + e1@M3

// d_ws layout (float offsets), all rows 20 floats = 80 B (16B-aligned)
#define OFF_G1   0      // [20][20] k-major
#define OFF_P1   400    // [20][20] m'-major
#define OFF_P2   800    // [20][20] k-major
#define OFF_M2   1200   // [3][20]  (M2r[c][m])
#define OFF_Q1   1260   // [3][20]  (Q1r[c][m'])
#define OFF_Q2   1320   // [3][20]  (Q2r[c][k])
#define OFF_B11  1380   // [20]
#define OFF_F2   1400   // [20]
#define OFF_F3   1420   // [3]
#define NWTOT    1423

__global__ void prep_kernel(const float* __restrict__ Wv, const float* __restrict__ Wres,
                            const float* __restrict__ W1, const float* __restrict__ b1,
                            const float* __restrict__ W2, const float* __restrict__ b2,
                            const float* __restrict__ W3, const float* __restrict__ b3,
                            const float* __restrict__ Wc, const float* __restrict__ bc,
                            float* __restrict__ W) {
    __shared__ float G2[400];   // [i][m]
    __shared__ float M3[60];    // [i][c]
    __shared__ float e1[20];
    const int tid = threadIdx.x;
    // ---- phase A: layer-1 folds ----
    for (int idx = tid; idx < 480; idx += 256) {
        if (idx < 400) {
            const int i = idx / 20, m = idx % 20;
            float s = 0.f;
            for (int j = 0; j < 20; ++j)
                s = fmaf(Wv[400 + j*20 + i] + Wres[400 + i*20 + j], W1[400 + m*20 + j], s);
            G2[idx] = s;
        } else if (idx < 460) {
            const int r = idx - 400, i = r / 3, c = r % 3;
            float s = 0.f;
            for (int p = 0; p < 20; ++p)
                s = fmaf(Wc[c*20 + p], W3[400 + p*20 + i], s);
            M3[r] = s;
        } else {
            const int j = idx - 460;
            e1[j] = b2[j] + b3[j];
        }
    }
    __syncthreads();
    // ---- phase B: final folded weights → d_ws ----
    for (int idx = tid; idx < NWTOT; idx += 256) {
        float s = 0.f;
        if (idx < 400) {                       // G1[k][m]
            const int k = idx / 20, m = idx % 20;
            for (int j = 0; j < 20; ++j)
                s = fmaf(Wv[j*20 + k] + Wres[k*20 + j], W1[m*20 + j], s);
        } else if (idx < 800) {                // P1[m'][m]
            const int r = idx - 400, mp = r / 20, m = r % 20;
            for (int i = 0; i < 20; ++i)
                s = fmaf(W2[i*20 + mp], G2[i*20 + m], s);
        } else if (idx < 1200) {               // P2[k][m]
            const int r = idx - 800, k = r / 20, m = r % 20;
            for (int i = 0; i < 20; ++i)
                s = fmaf(W3[i*20 + k], G2[i*20 + m], s);
        } else if (idx < 1260) {               // M2r[c][m]
            const int r = idx - 1200, c = r / 20, m = r % 20;
            for (int p = 0; p < 20; ++p)
                s = fmaf(Wc[c*20 + p], W2[400 + p*20 + m], s);
        } else if (idx < 1320) {               // Q1r[c][m']
            const int r = idx - 1260, c = r / 20, mp = r % 20;
            for (int i = 0; i < 20; ++i)
                s = fmaf(W2[i*20 + mp], M3[i*3 + c], s);
        } else if (idx < 1380) {               // Q2r[c][k]
            const int r = idx - 1320, c = r / 20, k = r % 20;
            for (int i = 0; i < 20; ++i)
                s = fmaf(W3[i*20 + k], M3[i*3 + c], s);
        } else if (idx < 1400) {               // b11
            s = b1[idx - 1380];
        } else if (idx < 1420) {               // f2
            const int m = idx - 1400;
            s = b1[20 + m];
            for (int i = 0; i < 20; ++i)
                s = fmaf(e1[i], G2[i*20 + m], s);
        } else {                               // f3
            const int c = idx - 1420;
            s = bc[c];
            for (int p = 0; p < 20; ++p)
                s = fmaf(Wc[c*20 + p], b2[20 + p] + b3[20 + p], s);
            for (int i = 0; i < 20; ++i)
                s = fmaf(e1[i], M3[i*3 + c], s);
        }
        W[idx] = s;
    }
}

// Weights are wave-uniform: read them through the SCALAR pipe (s_load via
// constant address space), so VALU FMAs take the weight as an SGPR operand.
// This removes all ~356 broadcast ds_read_b128 per pair-thread — the LDS
// pipe (one per CU, ~12 cyc/b128) was the measured bottleneck (136k cyc/CU
// vs 44k cyc/CU of FMA issue). Weights never touch VGPRs or LDS.
typedef float v4f __attribute__((ext_vector_type(4)));
typedef const __attribute__((address_space(4))) v4f  c4f_t;
typedef const __attribute__((address_space(4))) float cfl_t;

__global__ __launch_bounds__(256, 3) void fwd_kernel(const float* __restrict__ X,
                                                     const float* __restrict__ Wg,
                                                     float* __restrict__ out, int npair) {
    // integer round-trip cast: generic -> constant addrspace (s_load path)
    c4f_t* W4 = (c4f_t*)(unsigned long long)Wg;
    cfl_t* Wf = (cfl_t*)(unsigned long long)Wg;

    const int pair = blockIdx.x * blockDim.x + threadIdx.x;
    if (pair >= npair) return;

    // load 2 tokens (40 consecutive floats)
    float xa[20], xb[20];
    const float4* xp = reinterpret_cast<const float4*>(X + (size_t)pair * 40);
    #pragma unroll
    for (int q = 0; q < 5; ++q) {
        const float4 v = xp[q];
        xa[4*q+0] = v.x; xa[4*q+1] = v.y; xa[4*q+2] = v.z; xa[4*q+3] = v.w;
    }
    #pragma unroll
    for (int q = 0; q < 5; ++q) {
        const float4 v = xp[5 + q];
        xb[4*q+0] = v.x; xb[4*q+1] = v.y; xb[4*q+2] = v.z; xb[4*q+3] = v.w;
    }

    // h = relu(x @ G1 + b11)
    float ha[20], hb[20];
    #pragma unroll
    for (int q = 0; q < 5; ++q) {
        const v4f b = W4[OFF_B11/4 + q];
        ha[4*q+0] = b.x; ha[4*q+1] = b.y; ha[4*q+2] = b.z; ha[4*q+3] = b.w;
        hb[4*q+0] = b.x; hb[4*q+1] = b.y; hb[4*q+2] = b.z; hb[4*q+3] = b.w;
    }
    #pragma unroll
    for (int k = 0; k < 20; ++k) {
        const float x0 = xa[k], x1 = xb[k];
        #pragma unroll
        for (int q = 0; q < 5; ++q) {
            const v4f w = W4[OFF_G1/4 + k*5 + q];
            ha[4*q+0] = fmaf(x0, w.x, ha[4*q+0]); hb[4*q+0] = fmaf(x1, w.x, hb[4*q+0]);
            ha[4*q+1] = fmaf(x0, w.y, ha[4*q+1]); hb[4*q+1] = fmaf(x1, w.y, hb[4*q+1]);
            ha[4*q+2] = fmaf(x0, w.z, ha[4*q+2]); hb[4*q+2] = fmaf(x1, w.z, hb[4*q+2]);
            ha[4*q+3] = fmaf(x0, w.w, ha[4*q+3]); hb[4*q+3] = fmaf(x1, w.w, hb[4*q+3]);
        }
    }
    #pragma unroll
    for (int i = 0; i < 20; ++i) { ha[i] = fmaxf(ha[i], 0.f); hb[i] = fmaxf(hb[i], 0.f); }

    // g = relu(h @ P1 + x @ P2 + f2)
    float ga[20], gb[20];
    #pragma unroll
    for (int q = 0; q < 5; ++q) {
        const v4f b = W4[OFF_F2/4 + q];
        ga[4*q+0] = b.x; ga[4*q+1] = b.y; ga[4*q+2] = b.z; ga[4*q+3] = b.w;
        gb[4*q+0] = b.x; gb[4*q+1] = b.y; gb[4*q+2] = b.z; gb[4*q+3] = b.w;
    }
    #pragma unroll
    for (int k = 0; k < 20; ++k) {
        const float h0 = ha[k], h1 = hb[k];
        #pragma unroll
        for (int q = 0; q < 5; ++q) {
            const v4f w = W4[OFF_P1/4 + k*5 + q];
            ga[4*q+0] = fmaf(h0, w.x, ga[4*q+0]); gb[4*q+0] = fmaf(h1, w.x, gb[4*q+0]);
            ga[4*q+1] = fmaf(h0, w.y, ga[4*q+1]); gb[4*q+1] = fmaf(h1, w.y, gb[4*q+1]);
            ga[4*q+2] = fmaf(h0, w.z, ga[4*q+2]); gb[4*q+2] = fmaf(h1, w.z, gb[4*q+2]);
            ga[4*q+3] = fmaf(h0, w.w, ga[4*q+3]); gb[4*q+3] = fmaf(h1, w.w, gb[4*q+3]);
        }
        const float x0 = xa[k], x1 = xb[k];
        #pragma unroll
        for (int q = 0; q < 5; ++q) {
            const v4f w = W4[OFF_P2/4 + k*5 + q];
            ga[4*q+0] = fmaf(x0, w.x, ga[4*q+0]); gb[4*q+0] = fmaf(x1, w.x, gb[4*q+0]);
            ga[4*q+1] = fmaf(x0, w.y, ga[4*q+1]); gb[4*q+1] = fmaf(x1, w.y, gb[4*q+1]);
            ga[4*q+2] = fmaf(x0, w.z, ga[4*q+2]); gb[4*q+2] = fmaf(x1, w.z, gb[4*q+2]);
            ga[4*q+3] = fmaf(x0, w.w, ga[4*q+3]); gb[4*q+3] = fmaf(x1, w.w, gb[4*q+3]);
        }
    }
    #pragma unroll
    for (int i = 0; i < 20; ++i) { ga[i] = fmaxf(ga[i], 0.f); gb[i] = fmaxf(gb[i], 0.f); }

    // logits = g @ M2 + h @ Q1 + x @ Q2 + f3
    float la[3], lb[3];
    #pragma unroll
    for (int c = 0; c < 3; ++c) {
        float sa = Wf[OFF_F3 + c];
        float sb = sa;
        #pragma unroll
        for (int q = 0; q < 5; ++q) {
            const v4f wm  = W4[OFF_M2/4 + c*5 + q];
            const v4f wq1 = W4[OFF_Q1/4 + c*5 + q];
            const v4f wq2 = W4[OFF_Q2/4 + c*5 + q];
            sa = fmaf(ga[4*q+0], wm.x, sa);  sb = fmaf(gb[4*q+0], wm.x, sb);
            sa = fmaf(ga[4*q+1], wm.y, sa);  sb = fmaf(gb[4*q+1], wm.y, sb);
            sa = fmaf(ga[4*q+2], wm.z, sa);  sb = fmaf(gb[4*q+2], wm.z, sb);
            sa = fmaf(ga[4*q+3], wm.w, sa);  sb = fmaf(gb[4*q+3], wm.w, sb);
            sa = fmaf(ha[4*q+0], wq1.x, sa); sb = fmaf(hb[4*q+0], wq1.x, sb);
            sa = fmaf(ha[4*q+1], wq1.y, sa); sb = fmaf(hb[4*q+1], wq1.y, sb);
            sa = fmaf(ha[4*q+2], wq1.z, sa); sb = fmaf(hb[4*q+2], wq1.z, sb);
            sa = fmaf(ha[4*q+3], wq1.w, sa); sb = fmaf(hb[4*q+3], wq1.w, sb);
            sa = fmaf(xa[4*q+0], wq2.x, sa); sb = fmaf(xb[4*q+0], wq2.x, sb);
            sa = fmaf(xa[4*q+1], wq2.y, sa); sb = fmaf(xb[4*q+1], wq2.y, sb);
            sa = fmaf(xa[4*q+2], wq2.z, sa); sb = fmaf(xb[4*q+2], wq2.z, sb);
            sa = fmaf(xa[4*q+3], wq2.w, sa); sb = fmaf(xb[4*q+3], wq2.w, sb);
        }
        la[c] = sa; lb[c] = sb;
    }

    // softmax + store (2 tokens × 3 probs = 6 consecutive floats, 8B aligned)
    const float ma = fmaxf(fmaxf(la[0], la[1]), la[2]);
    const float ea0 = __expf(la[0] - ma), ea1 = __expf(la[1] - ma), ea2 = __expf(la[2] - ma);
    const float ra = 1.f / (ea0 + ea1 + ea2);
    const float mb = fmaxf(fmaxf(lb[0], lb[1]), lb[2]);
    const float eb0 = __expf(lb[0] - mb), eb1 = __expf(lb[1] - mb), eb2 = __expf(lb[2] - mb);
    const float rb = 1.f / (eb0 + eb1 + eb2);

    float2* o2 = reinterpret_cast<float2*>(out + (size_t)pair * 6);
    o2[0] = make_float2(ea0 * ra, ea1 * ra);
    o2[1] = make_float2(ea2 * ra, eb0 * rb);
    o2[2] = make_float2(eb1 * rb, eb2 * rb);
}

extern "C" void kernel_launch(void* const* d_in, const int* in_sizes, int n_in,
                              void* d_out, int out_size, void* d_ws, size_t ws_size,
                              hipStream_t stream) {
    const float* X    = (const float*)d_in[0];
    // d_in[1]=Wq, d_in[2]=Wk: dead (softmax over singleton axis == 1)
    const float* Wv   = (const float*)d_in[3];
    const float* Wres = (const float*)d_in[4];
    const float* W1   = (const float*)d_in[5];
    const float* b1   = (const float*)d_in[6];
    const float* W2   = (const float*)d_in[7];
    const float* b2   = (const float*)d_in[8];
    const float* W3   = (const float*)d_in[9];
    const float* b3   = (const float*)d_in[10];
    const float* Wc   = (const float*)d_in[11];
    const float* bc   = (const float*)d_in[12];
    float* out = (float*)d_out;
    float* W   = (float*)d_ws;

    const int S = in_sizes[0] / 20;
    const int npair = S / 2;   // S = 1048576 divides evenly

    prep_kernel<<<1, 256, 0, stream>>>(Wv, Wres, W1, b1, W2, b2, W3, b3, Wc, bc, W);

    const int block = 256;
    const int grid = (npair + block - 1) / block;
    fwd_kernel<<<grid, block, 0, stream>>>(X, W, out, npair);
}

// Round 2
// 172.446 us; speedup vs baseline: 1.0215x; 1.0215x over previous
//
#include <hip/hip_runtime.h>
#include <math.h>

// Folded model (exact algebra, per-token):
//   h      = relu(x @ G1 + b11)                      [400 MACs]
//   g      = relu(h @ P1 + x @ P2 + f2)              [800 MACs]
//   logits = g @ M2 + h @ Q1 + x @ Q2 + f3           [180 MACs]
//   out    = softmax(logits)
// where (layer arrays l=0 at offset 0, l=1 at offset 400):
//   A_l[i][j] = Wv_l[j][i] + Wres_l[i][j]
//   G_l[k][m] = sum_j A_l[k][j] * W1_l[m][j]       (A folded through W1)
//   C1[m'][i] = W2_0[i][m'] ; D1[k][i] = W3_0[i][k] ; e1 = b2_0 + b3_0
//   M2[m][c]  = sum_p Wc[c][p]*W2_1[p][m] ; M3[i][c] = sum_p Wc[c][p]*W3_1[p][i]
//   P1 = C1@G2 ; P2 = D1@G2 ; Q1 = C1@M3 ; Q2 = D1@M3
//   f2 = b1_1 + e1@G2 ; f3 = bc + Wc@(b2_1+b3_1) + e1@M3

// d_ws layout (float offsets), all rows 20 floats = 80 B (16B-aligned)
#define OFF_G1   0      // [20][20] k-major
#define OFF_P1   400    // [20][20] m'-major
#define OFF_P2   800    // [20][20] k-major
#define OFF_M2   1200   // [3][20]  (M2r[c][m])
#define OFF_Q1   1260   // [3][20]  (Q1r[c][m'])
#define OFF_Q2   1320   // [3][20]  (Q2r[c][k])
#define OFF_B11  1380   // [20]
#define OFF_F2   1400   // [20]
#define OFF_F3   1420   // [3]
#define NWTOT    1423

__global__ void prep_kernel(const float* __restrict__ Wv, const float* __restrict__ Wres,
                            const float* __restrict__ W1, const float* __restrict__ b1,
                            const float* __restrict__ W2, const float* __restrict__ b2,
                            const float* __restrict__ W3, const float* __restrict__ b3,
                            const float* __restrict__ Wc, const float* __restrict__ bc,
                            float* __restrict__ W) {
    __shared__ float G2[400];   // [i][m]
    __shared__ float M3[60];    // [i][c]
    __shared__ float e1[20];
    const int tid = threadIdx.x;
    // ---- phase A: layer-1 folds ----
    for (int idx = tid; idx < 480; idx += 256) {
        if (idx < 400) {
            const int i = idx / 20, m = idx % 20;
            float s = 0.f;
            for (int j = 0; j < 20; ++j)
                s = fmaf(Wv[400 + j*20 + i] + Wres[400 + i*20 + j], W1[400 + m*20 + j], s);
            G2[idx] = s;
        } else if (idx < 460) {
            const int r = idx - 400, i = r / 3, c = r % 3;
            float s = 0.f;
            for (int p = 0; p < 20; ++p)
                s = fmaf(Wc[c*20 + p], W3[400 + p*20 + i], s);
            M3[r] = s;
        } else {
            const int j = idx - 460;
            e1[j] = b2[j] + b3[j];
        }
    }
    __syncthreads();
    // ---- phase B: final folded weights → d_ws ----
    for (int idx = tid; idx < NWTOT; idx += 256) {
        float s = 0.f;
        if (idx < 400) {                       // G1[k][m]
            const int k = idx / 20, m = idx % 20;
            for (int j = 0; j < 20; ++j)
                s = fmaf(Wv[j*20 + k] + Wres[k*20 + j], W1[m*20 + j], s);
        } else if (idx < 800) {                // P1[m'][m]
            const int r = idx - 400, mp = r / 20, m = r % 20;
            for (int i = 0; i < 20; ++i)
                s = fmaf(W2[i*20 + mp], G2[i*20 + m], s);
        } else if (idx < 1200) {               // P2[k][m]
            const int r = idx - 800, k = r / 20, m = r % 20;
            for (int i = 0; i < 20; ++i)
                s = fmaf(W3[i*20 + k], G2[i*20 + m], s);
        } else if (idx < 1260) {               // M2r[c][m]
            const int r = idx - 1200, c = r / 20, m = r % 20;
            for (int p = 0; p < 20; ++p)
                s = fmaf(Wc[c*20 + p], W2[400 + p*20 + m], s);
        } else if (idx < 1320) {               // Q1r[c][m']
            const int r = idx - 1260, c = r / 20, mp = r % 20;
            for (int i = 0; i < 20; ++i)
                s = fmaf(W2[i*20 + mp], M3[i*3 + c], s);
        } else if (idx < 1380) {               // Q2r[c][k]
            const int r = idx - 1320, c = r / 20, k = r % 20;
            for (int i = 0; i < 20; ++i)
                s = fmaf(W3[i*20 + k], M3[i*3 + c], s);
        } else if (idx < 1400) {               // b11
            s = b1[idx - 1380];
        } else if (idx < 1420) {               // f2
            const int m = idx - 1400;
            s = b1[20 + m];
            for (int i = 0; i < 20; ++i)
                s = fmaf(e1[i], G2[i*20 + m], s);
        } else {                               // f3
            const int c = idx - 1420;
            s = bc[c];
            for (int p = 0; p < 20; ++p)
                s = fmaf(Wc[c*20 + p], b2[20 + p] + b3[20 + p], s);
            for (int i = 0; i < 20; ++i)
                s = fmaf(e1[i], M3[i*3 + c], s);
        }
        W[idx] = s;
    }
}

// T=1: one token per thread. Weights ride the SCALAR pipe (s_load via
// constant addrspace) so FMAs take the weight as an SGPR operand — zero
// LDS, zero weight VGPRs. T=1 keeps peak live state at x+h+g+la = 63
// floats (fits in regs); the previous T=2 version needed 126 live floats
// in a 68-VGPR budget, forcing remat/reload (~2x VALU inflation, the
// measured 56us vs 19us FMA floor). Logits contributions are folded in
// early (x@Q2 after load, h@Q1 after relu) so no extra state is carried.
typedef float v4f __attribute__((ext_vector_type(4)));
typedef const __attribute__((address_space(4))) v4f  c4f_t;
typedef const __attribute__((address_space(4))) float cfl_t;

__global__ __launch_bounds__(256, 6) void fwd_kernel(const float* __restrict__ X,
                                                     const float* __restrict__ Wg,
                                                     float* __restrict__ out, int ntok) {
    // integer round-trip cast: generic -> constant addrspace (s_load path)
    c4f_t* W4 = (c4f_t*)(unsigned long long)Wg;
    cfl_t* Wf = (cfl_t*)(unsigned long long)Wg;

    const int tid = blockIdx.x * blockDim.x + threadIdx.x;
    if (tid >= ntok) return;

    // load 1 token (20 consecutive floats, 16B-aligned: 80B/token)
    float x[20];
    const float4* xp = reinterpret_cast<const float4*>(X + (size_t)tid * 20);
    #pragma unroll
    for (int q = 0; q < 5; ++q) {
        const float4 v = xp[q];
        x[4*q+0] = v.x; x[4*q+1] = v.y; x[4*q+2] = v.z; x[4*q+3] = v.w;
    }

    // la = f3 + x @ Q2   (early: x is live anyway)
    float la[3];
    #pragma unroll
    for (int c = 0; c < 3; ++c) {
        float s = Wf[OFF_F3 + c];
        #pragma unroll
        for (int q = 0; q < 5; ++q) {
            const v4f w = W4[OFF_Q2/4 + c*5 + q];
            s = fmaf(x[4*q+0], w.x, s);
            s = fmaf(x[4*q+1], w.y, s);
            s = fmaf(x[4*q+2], w.z, s);
            s = fmaf(x[4*q+3], w.w, s);
        }
        la[c] = s;
    }

    // h = relu(x @ G1 + b11)
    float h[20];
    #pragma unroll
    for (int q = 0; q < 5; ++q) {
        const v4f b = W4[OFF_B11/4 + q];
        h[4*q+0] = b.x; h[4*q+1] = b.y; h[4*q+2] = b.z; h[4*q+3] = b.w;
    }
    #pragma unroll
    for (int k = 0; k < 20; ++k) {
        const float x0 = x[k];
        #pragma unroll
        for (int q = 0; q < 5; ++q) {
            const v4f w = W4[OFF_G1/4 + k*5 + q];
            h[4*q+0] = fmaf(x0, w.x, h[4*q+0]);
            h[4*q+1] = fmaf(x0, w.y, h[4*q+1]);
            h[4*q+2] = fmaf(x0, w.z, h[4*q+2]);
            h[4*q+3] = fmaf(x0, w.w, h[4*q+3]);
        }
    }
    #pragma unroll
    for (int i = 0; i < 20; ++i) h[i] = fmaxf(h[i], 0.f);

    // la += h @ Q1   (early: h is live anyway)
    #pragma unroll
    for (int c = 0; c < 3; ++c) {
        float s = la[c];
        #pragma unroll
        for (int q = 0; q < 5; ++q) {
            const v4f w = W4[OFF_Q1/4 + c*5 + q];
            s = fmaf(h[4*q+0], w.x, s);
            s = fmaf(h[4*q+1], w.y, s);
            s = fmaf(h[4*q+2], w.z, s);
            s = fmaf(h[4*q+3], w.w, s);
        }
        la[c] = s;
    }

    // g = relu(h @ P1 + x @ P2 + f2)
    float g[20];
    #pragma unroll
    for (int q = 0; q < 5; ++q) {
        const v4f b = W4[OFF_F2/4 + q];
        g[4*q+0] = b.x; g[4*q+1] = b.y; g[4*q+2] = b.z; g[4*q+3] = b.w;
    }
    #pragma unroll
    for (int k = 0; k < 20; ++k) {
        const float h0 = h[k];
        #pragma unroll
        for (int q = 0; q < 5; ++q) {
            const v4f w = W4[OFF_P1/4 + k*5 + q];
            g[4*q+0] = fmaf(h0, w.x, g[4*q+0]);
            g[4*q+1] = fmaf(h0, w.y, g[4*q+1]);
            g[4*q+2] = fmaf(h0, w.z, g[4*q+2]);
            g[4*q+3] = fmaf(h0, w.w, g[4*q+3]);
        }
        const float x0 = x[k];
        #pragma unroll
        for (int q = 0; q < 5; ++q) {
            const v4f w = W4[OFF_P2/4 + k*5 + q];
            g[4*q+0] = fmaf(x0, w.x, g[4*q+0]);
            g[4*q+1] = fmaf(x0, w.y, g[4*q+1]);
            g[4*q+2] = fmaf(x0, w.z, g[4*q+2]);
            g[4*q+3] = fmaf(x0, w.w, g[4*q+3]);
        }
    }
    #pragma unroll
    for (int i = 0; i < 20; ++i) g[i] = fmaxf(g[i], 0.f);

    // la += g @ M2
    #pragma unroll
    for (int c = 0; c < 3; ++c) {
        float s = la[c];
        #pragma unroll
        for (int q = 0; q < 5; ++q) {
            const v4f w = W4[OFF_M2/4 + c*5 + q];
            s = fmaf(g[4*q+0], w.x, s);
            s = fmaf(g[4*q+1], w.y, s);
            s = fmaf(g[4*q+2], w.z, s);
            s = fmaf(g[4*q+3], w.w, s);
        }
        la[c] = s;
    }

    // softmax + store (3 floats per token)
    const float m = fmaxf(fmaxf(la[0], la[1]), la[2]);
    const float e0 = __expf(la[0] - m), e1 = __expf(la[1] - m), e2 = __expf(la[2] - m);
    const float r = 1.f / (e0 + e1 + e2);
    float* o = out + (size_t)tid * 3;
    o[0] = e0 * r;
    o[1] = e1 * r;
    o[2] = e2 * r;
}

extern "C" void kernel_launch(void* const* d_in, const int* in_sizes, int n_in,
                              void* d_out, int out_size, void* d_ws, size_t ws_size,
                              hipStream_t stream) {
    const float* X    = (const float*)d_in[0];
    // d_in[1]=Wq, d_in[2]=Wk: dead (softmax over singleton axis == 1)
    const float* Wv   = (const float*)d_in[3];
    const float* Wres = (const float*)d_in[4];
    const float* W1   = (const float*)d_in[5];
    const float* b1   = (const float*)d_in[6];
    const float* W2   = (const float*)d_in[7];
    const float* b2   = (const float*)d_in[8];
    const float* W3   = (const float*)d_in[9];
    const float* b3   = (const float*)d_in[10];
    const float* Wc   = (const float*)d_in[11];
    const float* bc   = (const float*)d_in[12];
    float* out = (float*)d_out;
    float* W   = (float*)d_ws;

    const int S = in_sizes[0] / 20;

    prep_kernel<<<1, 256, 0, stream>>>(Wv, Wres, W1, b1, W2, b2, W3, b3, Wc, bc, W);

    const int block = 256;
    const int grid = (S + block - 1) / block;
    fwd_kernel<<<grid, block, 0, stream>>>(X, W, out, S);
}